// Round 16
// baseline (306.735 us; speedup 1.0000x reference)
//
#include <hip/hip_runtime.h>

// CapsuleFC: B=64, N=128, A=64, M=128, D=64
// out = [ncv (B*M*D) | na (B*M) | qk (B*N*M)], fp32
// R16: r15's barrier-free wave-private structure, but w staged via
// REGISTER loads (global_load_dwordx4 -> static double-buffer -> ds_write)
// instead of global_load_lds. Register path measured 4.8-6.4 TB/s vs
// DMA path's 2.3-2.9 across the whole session. LDS bytes/read path are
// bit-identical to r15 (passing, absmax 0.0078).
typedef __attribute__((ext_vector_type(8))) short bf16x8;
typedef __attribute__((ext_vector_type(4))) float f32x4;

constexpr int Bq = 64, Nq = 128, Aq = 64, Mq = 128, Dq = 64;
constexpr int MD = Mq * Dq;    // 8192
constexpr int NM = Nq * Mq;    // 16384
constexpr int NA = Nq * Aq;    // 8192
constexpr int NCV_SZ = Bq * MD;   // 524288
constexpr int NA_SZ  = Bq * Mq;   // 8192
constexpr float SCALE = 0.125f;   // 1/sqrt(64)

__device__ __forceinline__ unsigned short f2b(float f) {  // fp32 -> bf16 RNE
  unsigned u = __float_as_uint(f);
  return (unsigned short)((u + 0x7fffu + ((u >> 16) & 1u)) >> 16);
}
__device__ __forceinline__ unsigned cvt2(float lo, float hi) {
  return ((unsigned)f2b(hi) << 16) | (unsigned)f2b(lo);
}
__device__ __forceinline__ bf16x8 pack8(const float* v) {
  union { unsigned u[4]; bf16x8 b; } x;
  x.u[0] = cvt2(v[0], v[1]); x.u[1] = cvt2(v[2], v[3]);
  x.u[2] = cvt2(v[4], v[5]); x.u[3] = cvt2(v[6], v[7]);
  return x.b;
}

// ---------------- init: ncv = 0, na = 1 ----------------
__global__ __launch_bounds__(256) void k0_init(float* __restrict__ out) {
  int i = blockIdx.x * 256 + threadIdx.x;
  if (i < NCV_SZ) out[i] = 0.0f;
  else if (i < NCV_SZ + NA_SZ) out[i] = 1.0f;
}

// Per-wave half-tile LDS layout (8 KB), identical to r15:
// byte (al*1024 + l*16) holds w[a-row al*4+g][m-col, bytes (lr*16)^(swz<<6)],
// swz=(al>>1)&1. Read side applies the same XOR. (rule #21 both-sides.)

// ---------------- K1: logits, barrier-free, reg-staged w ----------------
// grid (mc=32, ns=16), block 256 = 4 waves; wave wv: m = mc*4+wv, full b.
// 8 n's per block, 16 half-tile phases, DESCENDING walk.
__global__ __launch_bounds__(256, 2) void k1_logits(
    const float* __restrict__ input, const float* __restrict__ ncvin,
    const float* __restrict__ wgt, float* __restrict__ logits) {
  const int mc = blockIdx.x;
  const int n0 = blockIdx.y * 8;
  const int t = threadIdx.x;
  const int wv = t >> 6, l = t & 63;
  const int lr = l & 15, g = l >> 4;
  const int m = mc * 4 + wv;
  __shared__ float Wr[4][2][2048];   // 4 waves x 2 slots x 8 KB = 64 KB

  // preload ncvin fragment (epilogue stays register-only)
  float cnv[4][4][4];
#pragma unroll
  for (int i = 0; i < 4; ++i)
#pragma unroll
    for (int j = 0; j < 4; ++j)
#pragma unroll
      for (int r = 0; r < 4; ++r)
        cnv[i][j][r] = ncvin[(size_t)(16 * i + 4 * g + r) * MD + m * Dq + 16 * j + lr];

  auto loadW = [&](int h, float4 (&R)[8]) {     // 8 coalesced dwordx4
    if (h > 15) return;
    const int hh = 15 - h;
    const int nn = n0 + (hh >> 1), ks = hh & 1;
    const char* wb = (const char*)wgt;
#pragma unroll
    for (int al = 0; al < 8; ++al) {
      const int swz = (al >> 1) & 1;
      const char* gs = wb + (size_t)(nn * 64 + ks * 32 + al * 4 + g) * 32768
                       + (size_t)m * 256 + ((lr * 16) ^ (swz << 6));
      R[al] = *(const float4*)gs;
    }
  };
  auto writeW = [&](int h, const float4 (&R)[8]) {  // ds_write_b128 x8, linear
    char* dst = (char*)&Wr[wv][h & 1][0];
#pragma unroll
    for (int al = 0; al < 8; ++al)
      *(float4*)(dst + al * 1024 + l * 16) = R[al];
  };
  auto loadAv = [&](int h, float (&av)[4][8]) {
    const int hh = 15 - h;
    const int nn = n0 + (hh >> 1), ks = hh & 1;
#pragma unroll
    for (int i = 0; i < 4; ++i) {
      const float* ap = input + (size_t)(16 * i + lr) * NA + nn * Aq + ks * 32 + g * 8;
      *(float4*)&av[i][0] = *(const float4*)ap;
      *(float4*)&av[i][4] = *(const float4*)(ap + 4);
    }
  };
  auto phase = [&](int h, float4 (&Rcur)[8], float4 (&Rnext)[8], f32x4 (&acc)[4][4]) {
    float av[4][8];
    loadAv(h, av);                       // av after W(h): wait below keeps av flying
    __builtin_amdgcn_sched_barrier(0);
    asm volatile("s_waitcnt vmcnt(8)" ::: "memory");   // retire W(h); av in flight
    writeW(h, Rcur);
    __builtin_amdgcn_sched_barrier(0);
    loadW(h + 1, Rnext);                 // W(h+1) in flight through compute
    __builtin_amdgcn_sched_barrier(0);
    asm volatile("s_waitcnt lgkmcnt(0)" ::: "memory"); // ds_writes visible
    __builtin_amdgcn_sched_barrier(0);

    if ((h & 1) == 0) {
#pragma unroll
      for (int i = 0; i < 4; ++i)
#pragma unroll
        for (int j = 0; j < 4; ++j) acc[i][j] = (f32x4)(0.0f);
    }
    bf16x8 af[4];
#pragma unroll
    for (int i = 0; i < 4; ++i) af[i] = pack8(av[i]);  // compiler waits av only

    const char* lb = (const char*)&Wr[wv][h & 1][0];
#pragma unroll
    for (int j = 0; j < 4; ++j) {
      float bv[8];
#pragma unroll
      for (int e = 0; e < 8; ++e)
        bv[e] = *(const float*)(lb + (g * 8 + e) * 256 + (((16 * j + lr) * 4) ^ ((g & 1) << 6)));
      bf16x8 bf = pack8(bv);
#pragma unroll
      for (int i = 0; i < 4; ++i)
        acc[i][j] = __builtin_amdgcn_mfma_f32_16x16x32_bf16(af[i], bf, acc[i][j], 0, 0, 0);
    }

    if (h & 1) {                         // epilogue (register-only + shfl + 1 store)
      const int nn = n0 + ((15 - h) >> 1);
      float lp[4][4];
#pragma unroll
      for (int i = 0; i < 4; ++i)
#pragma unroll
        for (int r = 0; r < 4; ++r) lp[i][r] = 0.0f;
#pragma unroll
      for (int i = 0; i < 4; ++i)
#pragma unroll
        for (int j = 0; j < 4; ++j)
#pragma unroll
          for (int r = 0; r < 4; ++r)
            lp[i][r] = fmaf(acc[i][j][r], cnv[i][j][r], lp[i][r]);
#pragma unroll
      for (int off = 1; off < 16; off <<= 1)
#pragma unroll
        for (int i = 0; i < 4; ++i)
#pragma unroll
          for (int r = 0; r < 4; ++r) lp[i][r] += __shfl_xor(lp[i][r], off);
      float ov = lp[0][0];
#pragma unroll
      for (int i = 0; i < 4; ++i)
#pragma unroll
        for (int r = 0; r < 4; ++r)
          ov = (lr == i * 4 + r) ? lp[i][r] : ov;
      const int b = 16 * (lr >> 2) + 4 * g + (lr & 3);
      logits[(size_t)b * NM + (size_t)nn * Mq + m] = SCALE * ov;
    }
  };

  float4 RA[8], RB[8];
  f32x4 acc[4][4];
  loadW(0, RA);
  for (int hp = 0; hp < 8; ++hp) {       // static RA/RB alternation (rule #20)
    phase(2 * hp,     RA, RB, acc);
    phase(2 * hp + 1, RB, RA, acc);
  }
}

// ---------------- K2: softmax + act modulation + renorm (in place) ----------------
__global__ __launch_bounds__(256) void k2_softmax(
    const float* __restrict__ next_act, float* __restrict__ qk) {
  const int row  = blockIdx.x * 4 + (threadIdx.x >> 6);
  const int lane = threadIdx.x & 63;
  const int b = row >> 7;
  float* p = qk + (size_t)row * Mq;
  float x0 = p[lane], x1 = p[lane + 64];
  float mx = fmaxf(x0, x1);
#pragma unroll
  for (int off = 32; off; off >>= 1) mx = fmaxf(mx, __shfl_xor(mx, off));
  float e0 = __expf(x0 - mx), e1 = __expf(x1 - mx);
  float s = e0 + e1;
#pragma unroll
  for (int off = 32; off; off >>= 1) s += __shfl_xor(s, off);
  float a0 = next_act[b * Mq + lane], a1 = next_act[b * Mq + lane + 64];
  float t0 = (e0 / s) * a0, t1 = (e1 / s) * a1;
  float s2 = t0 + t1;
#pragma unroll
  for (int off = 32; off; off >>= 1) s2 += __shfl_xor(s2, off);
  s2 += 1e-10f;
  p[lane]      = t0 / s2;
  p[lane + 64] = t1 / s2;
}

// ---------------- K3: aggregation, barrier-free, reg-staged w (ascending) ----------------
__global__ __launch_bounds__(256, 2) void k3_aggregate(
    const float* __restrict__ input, const float* __restrict__ cur_act,
    const float* __restrict__ wgt, const float* __restrict__ qk,
    float* __restrict__ ncv) {
  const int mc = blockIdx.x;
  const int n0 = blockIdx.y * 8;
  const int t = threadIdx.x;
  const int wv = t >> 6, l = t & 63;
  const int lr = l & 15, g = l >> 4;
  const int m = mc * 4 + wv;
  __shared__ float Wr[4][2][2048];   // 64 KB
  __shared__ float zl[8][4][64];     // 8 KB

  // pre-stage z = qk*cur_act once (only barrier, before steady state)
#pragma unroll
  for (int p = 0; p < 2; ++p) {
    const int idx = t + p * 256;
    const int b = idx >> 3, nn = idx & 7;
    float4 q4 = *(const float4*)&qk[(size_t)b * NM + (size_t)(n0 + nn) * Mq + mc * 4];
    float ca = cur_act[b * Nq + n0 + nn];
    zl[nn][0][b] = q4.x * ca; zl[nn][1][b] = q4.y * ca;
    zl[nn][2][b] = q4.z * ca; zl[nn][3][b] = q4.w * ca;
  }
  __syncthreads();

  auto loadW = [&](int h, float4 (&R)[8]) {
    if (h > 15) return;
    const int nn = n0 + (h >> 1), ks = h & 1;   // ascending walk
    const char* wb = (const char*)wgt;
#pragma unroll
    for (int al = 0; al < 8; ++al) {
      const int swz = (al >> 1) & 1;
      const char* gs = wb + (size_t)(nn * 64 + ks * 32 + al * 4 + g) * 32768
                       + (size_t)m * 256 + ((lr * 16) ^ (swz << 6));
      R[al] = *(const float4*)gs;
    }
  };
  auto writeW = [&](int h, const float4 (&R)[8]) {
    char* dst = (char*)&Wr[wv][h & 1][0];
#pragma unroll
    for (int al = 0; al < 8; ++al)
      *(float4*)(dst + al * 1024 + l * 16) = R[al];
  };
  auto loadAv = [&](int h, float (&av)[4][8]) {
    const int nn = n0 + (h >> 1), ks = h & 1;
#pragma unroll
    for (int i = 0; i < 4; ++i) {
      const float* ap = input + (size_t)(16 * i + lr) * NA + nn * Aq + ks * 32 + g * 8;
      *(float4*)&av[i][0] = *(const float4*)ap;
      *(float4*)&av[i][4] = *(const float4*)(ap + 4);
    }
  };

  float4 RA[8], RB[8];
  f32x4 acc[4][4];
#pragma unroll
  for (int i = 0; i < 4; ++i)
#pragma unroll
    for (int j = 0; j < 4; ++j) acc[i][j] = (f32x4)(0.0f);
  float zr[4];

  auto phase = [&](int h, float4 (&Rcur)[8], float4 (&Rnext)[8]) {
    float av[4][8];
    loadAv(h, av);
    __builtin_amdgcn_sched_barrier(0);
    asm volatile("s_waitcnt vmcnt(8)" ::: "memory");
    writeW(h, Rcur);
    __builtin_amdgcn_sched_barrier(0);
    loadW(h + 1, Rnext);
    __builtin_amdgcn_sched_barrier(0);
    asm volatile("s_waitcnt lgkmcnt(0)" ::: "memory");
    __builtin_amdgcn_sched_barrier(0);

    if ((h & 1) == 0) {
#pragma unroll
      for (int i = 0; i < 4; ++i) zr[i] = zl[h >> 1][wv][16 * i + lr];
    }
    bf16x8 af[4];
#pragma unroll
    for (int i = 0; i < 4; ++i) {
      float sv[8];
#pragma unroll
      for (int e = 0; e < 8; ++e) sv[e] = av[i][e] * zr[i];
      af[i] = pack8(sv);
    }
    const char* lb = (const char*)&Wr[wv][h & 1][0];
#pragma unroll
    for (int j = 0; j < 4; ++j) {
      float bv[8];
#pragma unroll
      for (int e = 0; e < 8; ++e)
        bv[e] = *(const float*)(lb + (g * 8 + e) * 256 + (((16 * j + lr) * 4) ^ ((g & 1) << 6)));
      bf16x8 bf = pack8(bv);
#pragma unroll
      for (int i = 0; i < 4; ++i)
        acc[i][j] = __builtin_amdgcn_mfma_f32_16x16x32_bf16(af[i], bf, acc[i][j], 0, 0, 0);
    }
  };

  loadW(0, RA);
  for (int hp = 0; hp < 8; ++hp) {
    phase(2 * hp,     RA, RB);
    phase(2 * hp + 1, RB, RA);
  }

  // epilogue: atomic partial sums over the 16 n-split blocks
#pragma unroll
  for (int i = 0; i < 4; ++i)
#pragma unroll
    for (int j = 0; j < 4; ++j) {
      const int d = 16 * j + lr;
#pragma unroll
      for (int r = 0; r < 4; ++r) {
        const int b = 16 * i + 4 * g + r;
        atomicAdd(&ncv[(size_t)b * MD + m * Dq + d], acc[i][j][r]);
      }
    }
}

extern "C" void kernel_launch(void* const* d_in, const int* in_sizes, int n_in,
                              void* d_out, int out_size, void* d_ws, size_t ws_size,
                              hipStream_t stream) {
  const float* input    = (const float*)d_in[0];
  const float* cur_act  = (const float*)d_in[1];
  const float* ncvin    = (const float*)d_in[2];
  const float* next_act = (const float*)d_in[3];
  const float* wgt      = (const float*)d_in[4];
  // d_in[5] = num_iter (unused by reference)

  float* out = (float*)d_out;
  float* ncv = out;
  float* qk  = out + NCV_SZ + NA_SZ;

  k0_init<<<(NCV_SZ + NA_SZ + 255) / 256, 256, 0, stream>>>(out);
  k1_logits<<<dim3(32, 16), 256, 0, stream>>>(input, ncvin, wgt, qk);
  k2_softmax<<<(Bq * Nq) / 4, 256, 0, stream>>>(next_act, qk);
  k3_aggregate<<<dim3(32, 16), 256, 0, stream>>>(input, cur_act, wgt, qk, ncv);
}

// Round 17
// 258.181 us; speedup vs baseline: 1.1881x; 1.1881x over previous
//
#include <hip/hip_runtime.h>

// CapsuleFC: B=64, N=128, A=64, M=128, D=64
// out = [ncv (B*M*D) | na (B*M) | qk (B*N*M)], fp32
// R17: k1 rewritten so w is consumed IN MEMORY ORDER (sequential register
// loads, the only >4 TB/s read mechanism measured): contract over d first:
//   logits[b,m] = sum_a X[b,a] * Y[a,b,m],  Y = sum_d w[n,a,m,d]*ncvin[b,m,d]
// => w is the MFMA A-operand with K=d (lane needs 8 consecutive d's = w's
// native layout). k3/k0/k2 = r15 verbatim (k3 is L3-warm).
typedef __attribute__((ext_vector_type(8))) short bf16x8;
typedef __attribute__((ext_vector_type(4))) float f32x4;
typedef __attribute__((ext_vector_type(4))) unsigned short us4;

constexpr int Bq = 64, Nq = 128, Aq = 64, Mq = 128, Dq = 64;
constexpr int MD = Mq * Dq;    // 8192
constexpr int NM = Nq * Mq;    // 16384
constexpr int NA = Nq * Aq;    // 8192
constexpr int NCV_SZ = Bq * MD;   // 524288
constexpr int NA_SZ  = Bq * Mq;   // 8192
constexpr float SCALE = 0.125f;   // 1/sqrt(64)
constexpr size_t NVB_BYTES = (size_t)Bq * MD * 2;   // 1 MiB bf16 ncvin

__device__ __forceinline__ unsigned short f2b(float f) {  // fp32 -> bf16 RNE
  unsigned u = __float_as_uint(f);
  return (unsigned short)((u + 0x7fffu + ((u >> 16) & 1u)) >> 16);
}
__device__ __forceinline__ unsigned cvt2(float lo, float hi) {
  return ((unsigned)f2b(hi) << 16) | (unsigned)f2b(lo);
}
__device__ __forceinline__ bf16x8 pack8(const float* v) {
  union { unsigned u[4]; bf16x8 b; } x;
  x.u[0] = cvt2(v[0], v[1]); x.u[1] = cvt2(v[2], v[3]);
  x.u[2] = cvt2(v[4], v[5]); x.u[3] = cvt2(v[6], v[7]);
  return x.b;
}
__device__ __forceinline__ void dma16(const float* g, float* l) {
  __builtin_amdgcn_global_load_lds(
      (const __attribute__((address_space(1))) unsigned*)g,
      (__attribute__((address_space(3))) unsigned*)l, 16, 0, 0);
}

// ---------------- init: ncv = 0, na = 1 ----------------
__global__ __launch_bounds__(256) void k0_init(float* __restrict__ out) {
  int i = blockIdx.x * 256 + threadIdx.x;
  if (i < NCV_SZ) out[i] = 0.0f;
  else if (i < NCV_SZ + NA_SZ) out[i] = 1.0f;
}

// ---------------- k_cv: ncvin fp32 -> bf16 (same [b][m][d] layout) ----------------
__global__ __launch_bounds__(256) void k_cv(const float* __restrict__ nv,
                                            us4* __restrict__ nvb) {
  int i = blockIdx.x * 256 + threadIdx.x;   // 131072 threads x float4
  float4 v = ((const float4*)nv)[i];
  us4 u; u[0] = f2b(v.x); u[1] = f2b(v.y); u[2] = f2b(v.z); u[3] = f2b(v.w);
  nvb[i] = u;
}

// ---------------- K1 (new): logits via d-contraction, sequential w ----------------
// grid (mq=4, n=128), block 256 (4 waves). Block owns (n, 32 m's).
// 4 phases x 16 a-rows; per phase stage w[16a][32m][64d] (8KB-contiguous rows)
// fp32->bf16 into 64KB LDS; MFMA Y_m(16a x 64b) = W_m(a x d) @ ncvinT_m(d x b);
// fold with X (registers) into lp[m][j]; reduce+store at end.
// LDS layout: byte(r,mm,d) = (r*4096 + mm*128 + d*2) ^ ((r&7)<<4).
template<int BF>
__global__ __launch_bounds__(256, 2) void k1_logits(
    const float* __restrict__ input,            // [B,N,A]
    const float* __restrict__ nvf,              // [B,M,D] fp32
    const unsigned short* __restrict__ nvb,     // [B,M,D] bf16 (if BF)
    const float* __restrict__ wgt,              // [N,A,M,D]
    float* __restrict__ logits) {               // [B,N,M] (qk region)
  const int mq = blockIdx.x;
  const int n  = blockIdx.y;
  const int t  = threadIdx.x;
  const int wv = t >> 6, l = t & 63;
  const int lr = l & 15, g = l >> 4;
  __shared__ char Ws[65536];    // 64 KB

  float lp[8][4];               // [mi][j] logits partials
#pragma unroll
  for (int mi = 0; mi < 8; ++mi)
#pragma unroll
    for (int j = 0; j < 4; ++j) lp[mi][j] = 0.0f;

  for (int ph = 0; ph < 4; ++ph) {
    // ---- stage: 32 x 4KB coalesced chunks (rows 8KB-contiguous) ----
#pragma unroll
    for (int batch = 0; batch < 4; ++batch) {
      float4 R[8];
#pragma unroll
      for (int u = 0; u < 8; ++u) {
        const int c = batch * 8 + u, r = c >> 1;
        const char* gs = (const char*)wgt + (size_t)(n * 64 + ph * 16 + r) * 32768
                         + (size_t)mq * 8192 + (c & 1) * 4096 + t * 16;
        R[u] = *(const float4*)gs;
      }
#pragma unroll
      for (int u = 0; u < 8; ++u) {
        const int c = batch * 8 + u, r = c >> 1;
        const int mm = (c & 1) * 16 + (t >> 4);
        const int dlo = (t & 15) * 4;
        us4 us; us[0] = f2b(R[u].x); us[1] = f2b(R[u].y);
        us[2] = f2b(R[u].z); us[3] = f2b(R[u].w);
        const int dst = (r * 4096 + mm * 128 + dlo * 2) ^ ((r & 7) << 4);
        *(us4*)(Ws + dst) = us;
      }
    }
    __syncthreads();

    // ---- compute: per wave 8 m's ----
    float xa[4][4];     // X[b=16j+lr][a=ph*16+4g+r]
#pragma unroll
    for (int j = 0; j < 4; ++j)
#pragma unroll
      for (int r = 0; r < 4; ++r)
        xa[j][r] = input[(size_t)(16 * j + lr) * NA + n * 64 + ph * 16 + 4 * g + r];

#pragma unroll
    for (int mi = 0; mi < 8; ++mi) {
      const int mm = wv * 8 + mi;
      const int ma = mq * 32 + mm;           // absolute m
      // B-frags: ncvin^T (K=d x col=b), 16B contiguous
      bf16x8 bfr[2][4];
#pragma unroll
      for (int ks = 0; ks < 2; ++ks)
#pragma unroll
        for (int j = 0; j < 4; ++j) {
          const size_t idx = (size_t)(16 * j + lr) * MD + ma * 64 + ks * 32 + g * 8;
          if (BF) {
            bfr[ks][j] = *(const bf16x8*)(nvb + idx);
          } else {
            float fv[8];
            *(float4*)&fv[0] = *(const float4*)(nvf + idx);
            *(float4*)&fv[4] = *(const float4*)(nvf + idx + 4);
            bfr[ks][j] = pack8(fv);
          }
        }
      // A-frags: W_m rows=a, K=d (from LDS)
      bf16x8 af[2];
#pragma unroll
      for (int ks = 0; ks < 2; ++ks)
        af[ks] = *(const bf16x8*)(Ws + ((lr * 4096 + mm * 128 + ks * 64 + g * 16)
                                        ^ ((lr & 7) << 4)));
      f32x4 acc[4];
#pragma unroll
      for (int j = 0; j < 4; ++j) acc[j] = (f32x4)(0.0f);
#pragma unroll
      for (int ks = 0; ks < 2; ++ks)
#pragma unroll
        for (int j = 0; j < 4; ++j)
          acc[j] = __builtin_amdgcn_mfma_f32_16x16x32_bf16(af[ks], bfr[ks][j], acc[j], 0, 0, 0);
      // fold: lp[mi][j] += Y[a=ph*16+4g+r][b=16j+lr] * X[b][a]
#pragma unroll
      for (int j = 0; j < 4; ++j)
#pragma unroll
        for (int r = 0; r < 4; ++r)
          lp[mi][j] = fmaf(acc[j][r], xa[j][r], lp[mi][j]);
    }
    __syncthreads();
  }

  // reduce over the 4 g-groups (a-subsets) and store
#pragma unroll
  for (int mi = 0; mi < 8; ++mi)
#pragma unroll
    for (int j = 0; j < 4; ++j) {
      float v = lp[mi][j];
      v += __shfl_xor(v, 16);
      v += __shfl_xor(v, 32);
      lp[mi][j] = v;
    }
#pragma unroll
  for (int mi2 = 0; mi2 < 2; ++mi2) {
    const int mi = g * 2 + mi2;
#pragma unroll
    for (int j = 0; j < 4; ++j) {
      const int b = 16 * j + lr;
      logits[(size_t)b * NM + (size_t)n * Mq + mq * 32 + wv * 8 + mi] = SCALE * lp[mi][j];
    }
  }
}

// ---------------- K2: softmax + act modulation + renorm (in place) ----------------
__global__ __launch_bounds__(256) void k2_softmax(
    const float* __restrict__ next_act, float* __restrict__ qk) {
  const int row  = blockIdx.x * 4 + (threadIdx.x >> 6);
  const int lane = threadIdx.x & 63;
  const int b = row >> 7;
  float* p = qk + (size_t)row * Mq;
  float x0 = p[lane], x1 = p[lane + 64];
  float mx = fmaxf(x0, x1);
#pragma unroll
  for (int off = 32; off; off >>= 1) mx = fmaxf(mx, __shfl_xor(mx, off));
  float e0 = __expf(x0 - mx), e1 = __expf(x1 - mx);
  float s = e0 + e1;
#pragma unroll
  for (int off = 32; off; off >>= 1) s += __shfl_xor(s, off);
  float a0 = next_act[b * Mq + lane], a1 = next_act[b * Mq + lane + 64];
  float t0 = (e0 / s) * a0, t1 = (e1 / s) * a1;
  float s2 = t0 + t1;
#pragma unroll
  for (int off = 32; off; off >>= 1) s2 += __shfl_xor(s2, off);
  s2 += 1e-10f;
  p[lane]      = t0 / s2;
  p[lane + 64] = t1 / s2;
}

// ---------------- K3: r15 verbatim (barrier-free wave-private DMA, ascending) ----
__global__ __launch_bounds__(256, 2) void k3_aggregate(
    const float* __restrict__ input, const float* __restrict__ cur_act,
    const float* __restrict__ wgt, const float* __restrict__ qk,
    float* __restrict__ ncv) {
  const int mc = blockIdx.x;
  const int n0 = blockIdx.y * 8;
  const int t = threadIdx.x;
  const int wv = t >> 6, l = t & 63;
  const int lr = l & 15, g = l >> 4;
  const int m = mc * 4 + wv;
  __shared__ float Wr[4][2][2048];   // 64 KB
  __shared__ float zl[8][4][64];     // 8 KB

#pragma unroll
  for (int p = 0; p < 2; ++p) {
    const int idx = t + p * 256;
    const int b = idx >> 3, nn = idx & 7;
    float4 q4 = *(const float4*)&qk[(size_t)b * NM + (size_t)(n0 + nn) * Mq + mc * 4];
    float ca = cur_act[b * Nq + n0 + nn];
    zl[nn][0][b] = q4.x * ca; zl[nn][1][b] = q4.y * ca;
    zl[nn][2][b] = q4.z * ca; zl[nn][3][b] = q4.w * ca;
  }
  __syncthreads();

  auto stageH = [&](int h) {
    if (h > 15) return;
    const int nn = n0 + (h >> 1), ks = h & 1;
    char* dst = (char*)&Wr[wv][h & 1][0];
    const char* wb = (const char*)wgt;
#pragma unroll
    for (int al = 0; al < 8; ++al) {
      const int swz = (al >> 1) & 1;
      const char* gs = wb + (size_t)(nn * 64 + ks * 32 + al * 4 + g) * 32768
                       + (size_t)m * 256 + ((lr * 16) ^ (swz << 6));
      dma16((const float*)gs, (float*)(dst + al * 1024));
    }
  };
  auto loadAv = [&](int h, float (&av)[4][8]) {
    const int nn = n0 + (h >> 1), ks = h & 1;
#pragma unroll
    for (int i = 0; i < 4; ++i) {
      const float* ap = input + (size_t)(16 * i + lr) * NA + nn * Aq + ks * 32 + g * 8;
      *(float4*)&av[i][0] = *(const float4*)ap;
      *(float4*)&av[i][4] = *(const float4*)(ap + 4);
    }
  };

  stageH(0);
  f32x4 acc[4][4];
#pragma unroll
  for (int i = 0; i < 4; ++i)
#pragma unroll
    for (int j = 0; j < 4; ++j) acc[i][j] = (f32x4)(0.0f);

  float zr[4];
  for (int h = 0; h < 16; ++h) {
    float av[4][8];
    loadAv(h, av);
    __builtin_amdgcn_sched_barrier(0);
    stageH(h + 1);
    __builtin_amdgcn_sched_barrier(0);
    if (h < 15) asm volatile("s_waitcnt vmcnt(16)" ::: "memory");
    else        asm volatile("s_waitcnt vmcnt(8)"  ::: "memory");
    __builtin_amdgcn_sched_barrier(0);

    if ((h & 1) == 0) {
#pragma unroll
      for (int i = 0; i < 4; ++i) zr[i] = zl[h >> 1][wv][16 * i + lr];
    }

    bf16x8 af[4];
#pragma unroll
    for (int i = 0; i < 4; ++i) {
      float sv[8];
#pragma unroll
      for (int e = 0; e < 8; ++e) sv[e] = av[i][e] * zr[i];
      af[i] = pack8(sv);
    }

    const char* lb = (const char*)&Wr[wv][h & 1][0];
#pragma unroll
    for (int j = 0; j < 4; ++j) {
      float bv[8];
#pragma unroll
      for (int e = 0; e < 8; ++e)
        bv[e] = *(const float*)(lb + (g * 8 + e) * 256 + (((16 * j + lr) * 4) ^ ((g & 1) << 6)));
      bf16x8 bf = pack8(bv);
#pragma unroll
      for (int i = 0; i < 4; ++i)
        acc[i][j] = __builtin_amdgcn_mfma_f32_16x16x32_bf16(af[i], bf, acc[i][j], 0, 0, 0);
    }
  }

#pragma unroll
  for (int i = 0; i < 4; ++i)
#pragma unroll
    for (int j = 0; j < 4; ++j) {
      const int d = 16 * j + lr;
#pragma unroll
      for (int r = 0; r < 4; ++r) {
        const int b = 16 * i + 4 * g + r;
        atomicAdd(&ncv[(size_t)b * MD + m * Dq + d], acc[i][j][r]);
      }
    }
}

extern "C" void kernel_launch(void* const* d_in, const int* in_sizes, int n_in,
                              void* d_out, int out_size, void* d_ws, size_t ws_size,
                              hipStream_t stream) {
  const float* input    = (const float*)d_in[0];
  const float* cur_act  = (const float*)d_in[1];
  const float* ncvin    = (const float*)d_in[2];
  const float* next_act = (const float*)d_in[3];
  const float* wgt      = (const float*)d_in[4];
  // d_in[5] = num_iter (unused by reference)

  float* out = (float*)d_out;
  float* ncv = out;
  float* qk  = out + NCV_SZ + NA_SZ;

  k0_init<<<(NCV_SZ + NA_SZ + 255) / 256, 256, 0, stream>>>(out);
  if (ws_size >= NVB_BYTES) {
    us4* nvb = (us4*)d_ws;
    k_cv<<<512, 256, 0, stream>>>(ncvin, nvb);
    k1_logits<1><<<dim3(4, Nq), 256, 0, stream>>>(input, ncvin,
        (const unsigned short*)nvb, wgt, qk);
  } else {
    k1_logits<0><<<dim3(4, Nq), 256, 0, stream>>>(input, ncvin,
        (const unsigned short*)nullptr, wgt, qk);
  }
  k2_softmax<<<(Bq * Nq) / 4, 256, 0, stream>>>(next_act, qk);
  k3_aggregate<<<dim3(32, 16), 256, 0, stream>>>(input, cur_act, wgt, qk, ncv);
}

// Round 18
// 205.769 us; speedup vs baseline: 1.4907x; 1.2547x over previous
//
#include <hip/hip_runtime.h>

// CapsuleFC: B=64, N=128, A=64, M=128, D=64
// out = [ncv (B*M*D) | na (B*M) | qk (B*N*M)], fp32
// R18: r15 barrier-free wave-private structure with 128-thr blocks (2 waves)
// -> 32KB LDS/block -> 5 blocks/CU = 10 miss-issuing waves/CU (was 8).
// All per-wave DMA/LDS/MFMA/epilogue code identical to r15 (passing).
typedef __attribute__((ext_vector_type(8))) short bf16x8;
typedef __attribute__((ext_vector_type(4))) float f32x4;

constexpr int Bq = 64, Nq = 128, Aq = 64, Mq = 128, Dq = 64;
constexpr int MD = Mq * Dq;    // 8192
constexpr int NM = Nq * Mq;    // 16384
constexpr int NA = Nq * Aq;    // 8192
constexpr int NCV_SZ = Bq * MD;   // 524288
constexpr int NA_SZ  = Bq * Mq;   // 8192
constexpr float SCALE = 0.125f;   // 1/sqrt(64)

__device__ __forceinline__ unsigned short f2b(float f) {  // fp32 -> bf16 RNE
  unsigned u = __float_as_uint(f);
  return (unsigned short)((u + 0x7fffu + ((u >> 16) & 1u)) >> 16);
}
__device__ __forceinline__ unsigned cvt2(float lo, float hi) {
  return ((unsigned)f2b(hi) << 16) | (unsigned)f2b(lo);
}
__device__ __forceinline__ bf16x8 pack8(const float* v) {
  union { unsigned u[4]; bf16x8 b; } x;
  x.u[0] = cvt2(v[0], v[1]); x.u[1] = cvt2(v[2], v[3]);
  x.u[2] = cvt2(v[4], v[5]); x.u[3] = cvt2(v[6], v[7]);
  return x.b;
}
__device__ __forceinline__ void dma16(const float* g, float* l) {
  __builtin_amdgcn_global_load_lds(
      (const __attribute__((address_space(1))) unsigned*)g,
      (__attribute__((address_space(3))) unsigned*)l, 16, 0, 0);
}

// ---------------- init: ncv = 0, na = 1 ----------------
__global__ __launch_bounds__(256) void k0_init(float* __restrict__ out) {
  int i = blockIdx.x * 256 + threadIdx.x;
  if (i < NCV_SZ) out[i] = 0.0f;
  else if (i < NCV_SZ + NA_SZ) out[i] = 1.0f;
}

// Per-wave half-tile LDS layout (8 KB), identical to r15:
// byte (al*1024 + l*16) holds w[a-row al*4+g][m-col, bytes (lr*16)^(swz<<6)],
// swz=(al>>1)&1; read side applies the same XOR (rule #21 both-sides).

// ---------------- K1: logits, barrier-free wave-private, 2-wave blocks ----------------
// grid (mc2=64, ns=16), block 128 = 2 waves; wave wv: m = mc2*2+wv, full b.
// 8 n's per block, 16 half-tile phases, DESCENDING walk (L3-cyclic with k3).
__global__ __launch_bounds__(128, 3) void k1_logits(
    const float* __restrict__ input, const float* __restrict__ ncvin,
    const float* __restrict__ wgt, float* __restrict__ logits) {
  const int mc2 = blockIdx.x;
  const int n0 = blockIdx.y * 8;
  const int t = threadIdx.x;
  const int wv = t >> 6, l = t & 63;
  const int lr = l & 15, g = l >> 4;
  const int m = mc2 * 2 + wv;
  __shared__ float Wr[2][2][2048];   // 2 waves x 2 slots x 8 KB = 32 KB

  // preload ncvin fragment (epilogue stays register-only)
  float cnv[4][4][4];
#pragma unroll
  for (int i = 0; i < 4; ++i)
#pragma unroll
    for (int j = 0; j < 4; ++j)
#pragma unroll
      for (int r = 0; r < 4; ++r)
        cnv[i][j][r] = ncvin[(size_t)(16 * i + 4 * g + r) * MD + m * Dq + 16 * j + lr];

  auto stageH = [&](int h) {         // stage half-tile h into slot h&1
    if (h > 15) return;
    const int hh = 15 - h;
    const int nn = n0 + (hh >> 1), ks = hh & 1;
    char* dst = (char*)&Wr[wv][h & 1][0];
    const char* wb = (const char*)wgt;
#pragma unroll
    for (int al = 0; al < 8; ++al) {
      const int swz = (al >> 1) & 1;
      const char* gs = wb + (size_t)(nn * 64 + ks * 32 + al * 4 + g) * 32768
                       + (size_t)m * 256 + ((lr * 16) ^ (swz << 6));
      dma16((const float*)gs, (float*)(dst + al * 1024));
    }
  };
  auto loadAv = [&](int h, float (&av)[4][8]) {
    const int hh = 15 - h;
    const int nn = n0 + (hh >> 1), ks = hh & 1;
#pragma unroll
    for (int i = 0; i < 4; ++i) {
      const float* ap = input + (size_t)(16 * i + lr) * NA + nn * Aq + ks * 32 + g * 8;
      *(float4*)&av[i][0] = *(const float4*)ap;
      *(float4*)&av[i][4] = *(const float4*)(ap + 4);
    }
  };

  stageH(0);
  f32x4 acc[4][4];
  for (int h = 0; h < 16; ++h) {
    float av[4][8];
    loadAv(h, av);                   // av BEFORE next DMAs (counter discipline)
    __builtin_amdgcn_sched_barrier(0);
    stageH(h + 1);
    __builtin_amdgcn_sched_barrier(0);
    // retire dma(h); keep av(h)+dma(h+1) in flight
    if (h < 15) asm volatile("s_waitcnt vmcnt(16)" ::: "memory");
    else        asm volatile("s_waitcnt vmcnt(8)"  ::: "memory");
    __builtin_amdgcn_sched_barrier(0);

    if ((h & 1) == 0) {
#pragma unroll
      for (int i = 0; i < 4; ++i)
#pragma unroll
        for (int j = 0; j < 4; ++j) acc[i][j] = (f32x4)(0.0f);
    }

    bf16x8 af[4];
#pragma unroll
    for (int i = 0; i < 4; ++i) af[i] = pack8(av[i]);   // compiler waits av only

    const char* lb = (const char*)&Wr[wv][h & 1][0];
#pragma unroll
    for (int j = 0; j < 4; ++j) {
      float bv[8];
#pragma unroll
      for (int e = 0; e < 8; ++e)
        bv[e] = *(const float*)(lb + (g * 8 + e) * 256 + (((16 * j + lr) * 4) ^ ((g & 1) << 6)));
      bf16x8 bf = pack8(bv);
#pragma unroll
      for (int i = 0; i < 4; ++i)
        acc[i][j] = __builtin_amdgcn_mfma_f32_16x16x32_bf16(af[i], bf, acc[i][j], 0, 0, 0);
    }

    if (h & 1) {                     // epilogue for nn (register-only + shfl + 1 store)
      const int nn = n0 + ((15 - h) >> 1);
      float lp[4][4];
#pragma unroll
      for (int i = 0; i < 4; ++i)
#pragma unroll
        for (int r = 0; r < 4; ++r) lp[i][r] = 0.0f;
#pragma unroll
      for (int i = 0; i < 4; ++i)
#pragma unroll
        for (int j = 0; j < 4; ++j)
#pragma unroll
          for (int r = 0; r < 4; ++r)
            lp[i][r] = fmaf(acc[i][j][r], cnv[i][j][r], lp[i][r]);
#pragma unroll
      for (int off = 1; off < 16; off <<= 1)
#pragma unroll
        for (int i = 0; i < 4; ++i)
#pragma unroll
          for (int r = 0; r < 4; ++r) lp[i][r] += __shfl_xor(lp[i][r], off);
      float ov = lp[0][0];
#pragma unroll
      for (int i = 0; i < 4; ++i)
#pragma unroll
        for (int r = 0; r < 4; ++r)
          ov = (lr == i * 4 + r) ? lp[i][r] : ov;
      const int b = 16 * (lr >> 2) + 4 * g + (lr & 3);
      logits[(size_t)b * NM + (size_t)nn * Mq + m] = SCALE * ov;
    }
  }
}

// ---------------- K2: softmax + act modulation + renorm (in place) ----------------
__global__ __launch_bounds__(256) void k2_softmax(
    const float* __restrict__ next_act, float* __restrict__ qk) {
  const int row  = blockIdx.x * 4 + (threadIdx.x >> 6);
  const int lane = threadIdx.x & 63;
  const int b = row >> 7;
  float* p = qk + (size_t)row * Mq;
  float x0 = p[lane], x1 = p[lane + 64];
  float mx = fmaxf(x0, x1);
#pragma unroll
  for (int off = 32; off; off >>= 1) mx = fmaxf(mx, __shfl_xor(mx, off));
  float e0 = __expf(x0 - mx), e1 = __expf(x1 - mx);
  float s = e0 + e1;
#pragma unroll
  for (int off = 32; off; off >>= 1) s += __shfl_xor(s, off);
  float a0 = next_act[b * Mq + lane], a1 = next_act[b * Mq + lane + 64];
  float t0 = (e0 / s) * a0, t1 = (e1 / s) * a1;
  float s2 = t0 + t1;
#pragma unroll
  for (int off = 32; off; off >>= 1) s2 += __shfl_xor(s2, off);
  s2 += 1e-10f;
  p[lane]      = t0 / s2;
  p[lane + 64] = t1 / s2;
}

// ---------------- K3: aggregation, barrier-free wave-private, 2-wave blocks ----
__global__ __launch_bounds__(128, 3) void k3_aggregate(
    const float* __restrict__ input, const float* __restrict__ cur_act,
    const float* __restrict__ wgt, const float* __restrict__ qk,
    float* __restrict__ ncv) {
  const int mc2 = blockIdx.x;
  const int n0 = blockIdx.y * 8;
  const int t = threadIdx.x;
  const int wv = t >> 6, l = t & 63;
  const int lr = l & 15, g = l >> 4;
  const int m = mc2 * 2 + wv;
  __shared__ float Wr[2][2][2048];   // 32 KB
  __shared__ float zl[8][2][64];     // 4 KB

  // pre-stage z = qk*cur_act once (only barrier, before steady state)
#pragma unroll
  for (int p = 0; p < 8; ++p) {
    const int idx = t + p * 128;     // 1024 = 64b x 8nn x 2mm
    const int b = idx >> 4, rem = idx & 15;
    const int nn = rem >> 1, mm = rem & 1;
    float q = qk[(size_t)b * NM + (size_t)(n0 + nn) * Mq + mc2 * 2 + mm];
    zl[nn][mm][b] = q * cur_act[b * Nq + n0 + nn];
  }
  __syncthreads();

  auto stageH = [&](int h) {         // ascending walk
    if (h > 15) return;
    const int nn = n0 + (h >> 1), ks = h & 1;
    char* dst = (char*)&Wr[wv][h & 1][0];
    const char* wb = (const char*)wgt;
#pragma unroll
    for (int al = 0; al < 8; ++al) {
      const int swz = (al >> 1) & 1;
      const char* gs = wb + (size_t)(nn * 64 + ks * 32 + al * 4 + g) * 32768
                       + (size_t)m * 256 + ((lr * 16) ^ (swz << 6));
      dma16((const float*)gs, (float*)(dst + al * 1024));
    }
  };
  auto loadAv = [&](int h, float (&av)[4][8]) {
    const int nn = n0 + (h >> 1), ks = h & 1;
#pragma unroll
    for (int i = 0; i < 4; ++i) {
      const float* ap = input + (size_t)(16 * i + lr) * NA + nn * Aq + ks * 32 + g * 8;
      *(float4*)&av[i][0] = *(const float4*)ap;
      *(float4*)&av[i][4] = *(const float4*)(ap + 4);
    }
  };

  stageH(0);
  f32x4 acc[4][4];
#pragma unroll
  for (int i = 0; i < 4; ++i)
#pragma unroll
    for (int j = 0; j < 4; ++j) acc[i][j] = (f32x4)(0.0f);

  float zr[4];
  for (int h = 0; h < 16; ++h) {
    float av[4][8];
    loadAv(h, av);
    __builtin_amdgcn_sched_barrier(0);
    stageH(h + 1);
    __builtin_amdgcn_sched_barrier(0);
    if (h < 15) asm volatile("s_waitcnt vmcnt(16)" ::: "memory");
    else        asm volatile("s_waitcnt vmcnt(8)"  ::: "memory");
    __builtin_amdgcn_sched_barrier(0);

    if ((h & 1) == 0) {
#pragma unroll
      for (int i = 0; i < 4; ++i) zr[i] = zl[h >> 1][wv][16 * i + lr];
    }

    bf16x8 af[4];
#pragma unroll
    for (int i = 0; i < 4; ++i) {
      float sv[8];
#pragma unroll
      for (int e = 0; e < 8; ++e) sv[e] = av[i][e] * zr[i];
      af[i] = pack8(sv);
    }

    const char* lb = (const char*)&Wr[wv][h & 1][0];
#pragma unroll
    for (int j = 0; j < 4; ++j) {
      float bv[8];
#pragma unroll
      for (int e = 0; e < 8; ++e)
        bv[e] = *(const float*)(lb + (g * 8 + e) * 256 + (((16 * j + lr) * 4) ^ ((g & 1) << 6)));
      bf16x8 bf = pack8(bv);
#pragma unroll
      for (int i = 0; i < 4; ++i)
        acc[i][j] = __builtin_amdgcn_mfma_f32_16x16x32_bf16(af[i], bf, acc[i][j], 0, 0, 0);
    }
  }

  // epilogue: atomic partial sums over the 16 n-split blocks
#pragma unroll
  for (int i = 0; i < 4; ++i)
#pragma unroll
    for (int j = 0; j < 4; ++j) {
      const int d = 16 * j + lr;
#pragma unroll
      for (int r = 0; r < 4; ++r) {
        const int b = 16 * i + 4 * g + r;
        atomicAdd(&ncv[(size_t)b * MD + m * Dq + d], acc[i][j][r]);
      }
    }
}

extern "C" void kernel_launch(void* const* d_in, const int* in_sizes, int n_in,
                              void* d_out, int out_size, void* d_ws, size_t ws_size,
                              hipStream_t stream) {
  const float* input    = (const float*)d_in[0];
  const float* cur_act  = (const float*)d_in[1];
  const float* ncvin    = (const float*)d_in[2];
  const float* next_act = (const float*)d_in[3];
  const float* wgt      = (const float*)d_in[4];
  // d_in[5] = num_iter (unused by reference)

  float* out = (float*)d_out;
  float* ncv = out;
  float* qk  = out + NCV_SZ + NA_SZ;

  k0_init<<<(NCV_SZ + NA_SZ + 255) / 256, 256, 0, stream>>>(out);
  k1_logits<<<dim3(64, 16), 128, 0, stream>>>(input, ncvin, wgt, qk);
  k2_softmax<<<(Bq * Nq) / 4, 256, 0, stream>>>(next_act, qk);
  k3_aggregate<<<dim3(64, 16), 128, 0, stream>>>(input, cur_act, wgt, qk, ncv);
}

// Round 19
// 144.631 us; speedup vs baseline: 2.1208x; 1.4227x over previous
//
#include <hip/hip_runtime.h>

// CapsuleFC: B=64, N=128, A=64, M=128, D=64
// out = [ncv (B*M*D) | na (B*M) | qk (B*N*M)], fp32
// R19: REVERT to r15 (session best, 144.35us verified): zero steady-state
// barriers, 4 waves/block, wave-private 2-slot LDS rings (8KB half-tiles),
// own-vmcnt discipline, full-b per-wave MFMA math. 2 blocks/CU.
typedef __attribute__((ext_vector_type(8))) short bf16x8;
typedef __attribute__((ext_vector_type(4))) float f32x4;

constexpr int Bq = 64, Nq = 128, Aq = 64, Mq = 128, Dq = 64;
constexpr int MD = Mq * Dq;    // 8192
constexpr int NM = Nq * Mq;    // 16384
constexpr int NA = Nq * Aq;    // 8192
constexpr int NCV_SZ = Bq * MD;   // 524288
constexpr int NA_SZ  = Bq * Mq;   // 8192
constexpr float SCALE = 0.125f;   // 1/sqrt(64)

__device__ __forceinline__ unsigned short f2b(float f) {  // fp32 -> bf16 RNE
  unsigned u = __float_as_uint(f);
  return (unsigned short)((u + 0x7fffu + ((u >> 16) & 1u)) >> 16);
}
__device__ __forceinline__ unsigned cvt2(float lo, float hi) {
  return ((unsigned)f2b(hi) << 16) | (unsigned)f2b(lo);
}
__device__ __forceinline__ bf16x8 pack8(const float* v) {
  union { unsigned u[4]; bf16x8 b; } x;
  x.u[0] = cvt2(v[0], v[1]); x.u[1] = cvt2(v[2], v[3]);
  x.u[2] = cvt2(v[4], v[5]); x.u[3] = cvt2(v[6], v[7]);
  return x.b;
}
__device__ __forceinline__ void dma16(const float* g, float* l) {
  __builtin_amdgcn_global_load_lds(
      (const __attribute__((address_space(1))) unsigned*)g,
      (__attribute__((address_space(3))) unsigned*)l, 16, 0, 0);
}

// ---------------- init: ncv = 0, na = 1 ----------------
__global__ __launch_bounds__(256) void k0_init(float* __restrict__ out) {
  int i = blockIdx.x * 256 + threadIdx.x;
  if (i < NCV_SZ) out[i] = 0.0f;
  else if (i < NCV_SZ + NA_SZ) out[i] = 1.0f;
}

// Per-wave half-tile LDS layout (8 KB): LDS[r=32 rows][256 B], where
// LDS[r][c] = W[a=ks*32+r][byte c ^ (((r>>3)&1)<<6)] of the wave's m-column.
// Store side: DMA al covers rows al*4..+3, swz=(al>>1)&1 uniform per instr
// (applied to the GLOBAL source per rule #21); read side applies same XOR.

// ---------------- K1: logits, barrier-free wave-private pipeline ----------------
// grid (mc=32, ns=16), block 256 = 4 waves; wave wv: m = mc*4+wv, full b.
// 8 n's per block, 16 half-tile phases, DESCENDING walk (L3-cyclic with k3).
__global__ __launch_bounds__(256, 2) void k1_logits(
    const float* __restrict__ input, const float* __restrict__ ncvin,
    const float* __restrict__ wgt, float* __restrict__ logits) {
  const int mc = blockIdx.x;
  const int n0 = blockIdx.y * 8;
  const int t = threadIdx.x;
  const int wv = t >> 6, l = t & 63;
  const int lr = l & 15, g = l >> 4;
  const int m = mc * 4 + wv;
  __shared__ float Wr[4][2][2048];   // 4 waves x 2 slots x 8 KB = 64 KB

  // preload ncvin fragment (epilogue is register-only afterwards)
  float cnv[4][4][4];
#pragma unroll
  for (int i = 0; i < 4; ++i)
#pragma unroll
    for (int j = 0; j < 4; ++j)
#pragma unroll
      for (int r = 0; r < 4; ++r)
        cnv[i][j][r] = ncvin[(size_t)(16 * i + 4 * g + r) * MD + m * Dq + 16 * j + lr];

  auto stageH = [&](int h) {         // stage half-tile h into slot h&1
    if (h > 15) return;
    const int hh = 15 - h;
    const int nn = n0 + (hh >> 1), ks = hh & 1;
    char* dst = (char*)&Wr[wv][h & 1][0];
    const char* wb = (const char*)wgt;
#pragma unroll
    for (int al = 0; al < 8; ++al) {
      const int swz = (al >> 1) & 1;
      const char* gs = wb + (size_t)(nn * 64 + ks * 32 + al * 4 + g) * 32768
                       + (size_t)m * 256 + ((lr * 16) ^ (swz << 6));
      dma16((const float*)gs, (float*)(dst + al * 1024));
    }
  };
  auto loadAv = [&](int h, float (&av)[4][8]) {
    const int hh = 15 - h;
    const int nn = n0 + (hh >> 1), ks = hh & 1;
#pragma unroll
    for (int i = 0; i < 4; ++i) {
      const float* ap = input + (size_t)(16 * i + lr) * NA + nn * Aq + ks * 32 + g * 8;
      *(float4*)&av[i][0] = *(const float4*)ap;
      *(float4*)&av[i][4] = *(const float4*)(ap + 4);
    }
  };

  stageH(0);
  f32x4 acc[4][4];
  for (int h = 0; h < 16; ++h) {
    float av[4][8];
    loadAv(h, av);                   // av BEFORE next DMAs (counter discipline)
    __builtin_amdgcn_sched_barrier(0);
    stageH(h + 1);
    __builtin_amdgcn_sched_barrier(0);
    // retire dma(h) (+any old store); keep av(h)+dma(h+1) in flight
    if (h < 15) asm volatile("s_waitcnt vmcnt(16)" ::: "memory");
    else        asm volatile("s_waitcnt vmcnt(8)"  ::: "memory");
    __builtin_amdgcn_sched_barrier(0);

    if ((h & 1) == 0) {
#pragma unroll
      for (int i = 0; i < 4; ++i)
#pragma unroll
        for (int j = 0; j < 4; ++j) acc[i][j] = (f32x4)(0.0f);
    }

    bf16x8 af[4];
#pragma unroll
    for (int i = 0; i < 4; ++i) af[i] = pack8(av[i]);   // compiler waits av only

    const char* lb = (const char*)&Wr[wv][h & 1][0];
#pragma unroll
    for (int j = 0; j < 4; ++j) {
      float bv[8];
#pragma unroll
      for (int e = 0; e < 8; ++e)
        bv[e] = *(const float*)(lb + (g * 8 + e) * 256 + (((16 * j + lr) * 4) ^ ((g & 1) << 6)));
      bf16x8 bf = pack8(bv);
#pragma unroll
      for (int i = 0; i < 4; ++i)
        acc[i][j] = __builtin_amdgcn_mfma_f32_16x16x32_bf16(af[i], bf, acc[i][j], 0, 0, 0);
    }

    if (h & 1) {                     // epilogue for nn (register-only + shfl + 1 store)
      const int nn = n0 + ((15 - h) >> 1);
      float lp[4][4];
#pragma unroll
      for (int i = 0; i < 4; ++i)
#pragma unroll
        for (int r = 0; r < 4; ++r) lp[i][r] = 0.0f;
#pragma unroll
      for (int i = 0; i < 4; ++i)
#pragma unroll
        for (int j = 0; j < 4; ++j)
#pragma unroll
          for (int r = 0; r < 4; ++r)
            lp[i][r] = fmaf(acc[i][j][r], cnv[i][j][r], lp[i][r]);
#pragma unroll
      for (int off = 1; off < 16; off <<= 1)
#pragma unroll
        for (int i = 0; i < 4; ++i)
#pragma unroll
          for (int r = 0; r < 4; ++r) lp[i][r] += __shfl_xor(lp[i][r], off);
      float ov = lp[0][0];
#pragma unroll
      for (int i = 0; i < 4; ++i)
#pragma unroll
        for (int r = 0; r < 4; ++r)
          ov = (lr == i * 4 + r) ? lp[i][r] : ov;
      const int b = 16 * (lr >> 2) + 4 * g + (lr & 3);
      logits[(size_t)b * NM + (size_t)nn * Mq + m] = SCALE * ov;
    }
  }
}

// ---------------- K2: softmax + act modulation + renorm (in place) ----------------
__global__ __launch_bounds__(256) void k2_softmax(
    const float* __restrict__ next_act, float* __restrict__ qk) {
  const int row  = blockIdx.x * 4 + (threadIdx.x >> 6);
  const int lane = threadIdx.x & 63;
  const int b = row >> 7;
  float* p = qk + (size_t)row * Mq;
  float x0 = p[lane], x1 = p[lane + 64];
  float mx = fmaxf(x0, x1);
#pragma unroll
  for (int off = 32; off; off >>= 1) mx = fmaxf(mx, __shfl_xor(mx, off));
  float e0 = __expf(x0 - mx), e1 = __expf(x1 - mx);
  float s = e0 + e1;
#pragma unroll
  for (int off = 32; off; off >>= 1) s += __shfl_xor(s, off);
  float a0 = next_act[b * Mq + lane], a1 = next_act[b * Mq + lane + 64];
  float t0 = (e0 / s) * a0, t1 = (e1 / s) * a1;
  float s2 = t0 + t1;
#pragma unroll
  for (int off = 32; off; off >>= 1) s2 += __shfl_xor(s2, off);
  s2 += 1e-10f;
  p[lane]      = t0 / s2;
  p[lane + 64] = t1 / s2;
}

// ---------------- K3: aggregation, barrier-free wave-private (ascending) ----------------
__global__ __launch_bounds__(256, 2) void k3_aggregate(
    const float* __restrict__ input, const float* __restrict__ cur_act,
    const float* __restrict__ wgt, const float* __restrict__ qk,
    float* __restrict__ ncv) {
  const int mc = blockIdx.x;
  const int n0 = blockIdx.y * 8;
  const int t = threadIdx.x;
  const int wv = t >> 6, l = t & 63;
  const int lr = l & 15, g = l >> 4;
  const int m = mc * 4 + wv;
  __shared__ float Wr[4][2][2048];   // 64 KB
  __shared__ float zl[8][4][64];     // 8 KB

  // pre-stage z = qk*cur_act once (the ONLY barrier, before any DMA)
#pragma unroll
  for (int p = 0; p < 2; ++p) {
    const int idx = t + p * 256;
    const int b = idx >> 3, nn = idx & 7;
    float4 q4 = *(const float4*)&qk[(size_t)b * NM + (size_t)(n0 + nn) * Mq + mc * 4];
    float ca = cur_act[b * Nq + n0 + nn];
    zl[nn][0][b] = q4.x * ca; zl[nn][1][b] = q4.y * ca;
    zl[nn][2][b] = q4.z * ca; zl[nn][3][b] = q4.w * ca;
  }
  __syncthreads();

  auto stageH = [&](int h) {         // ascending walk
    if (h > 15) return;
    const int nn = n0 + (h >> 1), ks = h & 1;
    char* dst = (char*)&Wr[wv][h & 1][0];
    const char* wb = (const char*)wgt;
#pragma unroll
    for (int al = 0; al < 8; ++al) {
      const int swz = (al >> 1) & 1;
      const char* gs = wb + (size_t)(nn * 64 + ks * 32 + al * 4 + g) * 32768
                       + (size_t)m * 256 + ((lr * 16) ^ (swz << 6));
      dma16((const float*)gs, (float*)(dst + al * 1024));
    }
  };
  auto loadAv = [&](int h, float (&av)[4][8]) {
    const int nn = n0 + (h >> 1), ks = h & 1;
#pragma unroll
    for (int i = 0; i < 4; ++i) {
      const float* ap = input + (size_t)(16 * i + lr) * NA + nn * Aq + ks * 32 + g * 8;
      *(float4*)&av[i][0] = *(const float4*)ap;
      *(float4*)&av[i][4] = *(const float4*)(ap + 4);
    }
  };

  stageH(0);
  f32x4 acc[4][4];
#pragma unroll
  for (int i = 0; i < 4; ++i)
#pragma unroll
    for (int j = 0; j < 4; ++j) acc[i][j] = (f32x4)(0.0f);

  float zr[4];
  for (int h = 0; h < 16; ++h) {
    float av[4][8];
    loadAv(h, av);
    __builtin_amdgcn_sched_barrier(0);
    stageH(h + 1);
    __builtin_amdgcn_sched_barrier(0);
    if (h < 15) asm volatile("s_waitcnt vmcnt(16)" ::: "memory");
    else        asm volatile("s_waitcnt vmcnt(8)"  ::: "memory");
    __builtin_amdgcn_sched_barrier(0);

    if ((h & 1) == 0) {
#pragma unroll
      for (int i = 0; i < 4; ++i) zr[i] = zl[h >> 1][wv][16 * i + lr];
    }

    bf16x8 af[4];
#pragma unroll
    for (int i = 0; i < 4; ++i) {
      float sv[8];
#pragma unroll
      for (int e = 0; e < 8; ++e) sv[e] = av[i][e] * zr[i];
      af[i] = pack8(sv);
    }

    const char* lb = (const char*)&Wr[wv][h & 1][0];
#pragma unroll
    for (int j = 0; j < 4; ++j) {
      float bv[8];
#pragma unroll
      for (int e = 0; e < 8; ++e)
        bv[e] = *(const float*)(lb + (g * 8 + e) * 256 + (((16 * j + lr) * 4) ^ ((g & 1) << 6)));
      bf16x8 bf = pack8(bv);
#pragma unroll
      for (int i = 0; i < 4; ++i)
        acc[i][j] = __builtin_amdgcn_mfma_f32_16x16x32_bf16(af[i], bf, acc[i][j], 0, 0, 0);
    }
  }

  // epilogue: atomic partial sums over the 16 n-split blocks
#pragma unroll
  for (int i = 0; i < 4; ++i)
#pragma unroll
    for (int j = 0; j < 4; ++j) {
      const int d = 16 * j + lr;
#pragma unroll
      for (int r = 0; r < 4; ++r) {
        const int b = 16 * i + 4 * g + r;
        atomicAdd(&ncv[(size_t)b * MD + m * Dq + d], acc[i][j][r]);
      }
    }
}

extern "C" void kernel_launch(void* const* d_in, const int* in_sizes, int n_in,
                              void* d_out, int out_size, void* d_ws, size_t ws_size,
                              hipStream_t stream) {
  const float* input    = (const float*)d_in[0];
  const float* cur_act  = (const float*)d_in[1];
  const float* ncvin    = (const float*)d_in[2];
  const float* next_act = (const float*)d_in[3];
  const float* wgt      = (const float*)d_in[4];
  // d_in[5] = num_iter (unused by reference)

  float* out = (float*)d_out;
  float* ncv = out;
  float* qk  = out + NCV_SZ + NA_SZ;

  k0_init<<<(NCV_SZ + NA_SZ + 255) / 256, 256, 0, stream>>>(out);
  k1_logits<<<dim3(32, 16), 256, 0, stream>>>(input, ncvin, wgt, qk);
  k2_softmax<<<(Bq * Nq) / 4, 256, 0, stream>>>(next_act, qk);
  k3_aggregate<<<dim3(32, 16), 256, 0, stream>>>(input, cur_act, wgt, qk, ncv);
}